// Round 3
// baseline (472.412 us; speedup 1.0000x reference)
//
#include <hip/hip_runtime.h>
#include <math.h>

#define M0 128
#define M1 64
#define M2 32
#define DIMN 480      // 128 + 3*64 + 5*32
#define MSGC 64
#define NBLK 3
#define RBFD 32
#define NT 2048       // r-table resolution
#define TCHUNK 32     // t-values per k_rtab block
#define NPB 8         // nodes per k_out block
#define FCUT 5.0f

// 48-byte dst-sorted edge record
struct __align__(16) ERec {
    int   src;
    int   ti;
    float fr;
    float fc;
    float sh[8];   // sh1..sh8
};

// ---------- pass 1: count edges per dst ----------
__global__ void k_count(const int* __restrict__ dst, int* __restrict__ counts, int E) {
    int e = blockIdx.x * blockDim.x + threadIdx.x;
    if (e >= E) return;
    atomicAdd(&counts[dst[e]], 1);
}

// ---------- exclusive prefix scan of counts (single block) ----------
__global__ void k_scan(const int* __restrict__ counts, int* __restrict__ offs,
                       int* __restrict__ cursor, int n) {
    __shared__ int buf[4096];
    for (int i = threadIdx.x; i < n; i += blockDim.x) buf[i] = counts[i];
    __syncthreads();
    for (int d = 1; d < n; d <<= 1) {
        int vals[4];
        int k = 0;
        for (int i = threadIdx.x; i < n; i += blockDim.x, ++k)
            vals[k] = (i >= d) ? buf[i - d] : 0;
        __syncthreads();
        k = 0;
        for (int i = threadIdx.x; i < n; i += blockDim.x, ++k)
            buf[i] += vals[k];
        __syncthreads();
    }
    for (int i = threadIdx.x; i < n; i += blockDim.x) {
        int excl = (i == 0) ? 0 : buf[i - 1];
        offs[i] = excl;
        cursor[i] = excl;
    }
    if (threadIdx.x == 0) offs[n] = buf[n - 1];
}

// ---------- pass 2: edge features scattered into dst order ----------
__global__ void k_build(const float* __restrict__ ew, const float* __restrict__ ev,
                        const int* __restrict__ src, const int* __restrict__ dst,
                        int* __restrict__ cursor, ERec* __restrict__ rec, int E) {
    int e = blockIdx.x * blockDim.x + threadIdx.x;
    if (e >= E) return;
    float len = ew[e];
    float inv = 1.0f / fmaxf(len, 1e-8f);
    float x = ev[e * 3 + 0] * inv;
    float y = ev[e * 3 + 1] * inv;
    float z = ev[e * 3 + 2] * inv;
    const float s3 = 1.7320508075688772f, s5 = 2.23606797749979f, s15 = 3.872983346207417f;
    ERec r;
    r.src = src[e];
    float u = fminf(len, FCUT) * ((float)(NT - 1) / FCUT);
    int ti = (int)u;
    ti = min(ti, NT - 2);
    r.ti = ti;
    r.fr = u - (float)ti;
    float t = fminf(len / FCUT, 1.0f);
    r.fc = 0.5f * (cosf(3.14159265358979323846f * t) + 1.0f);
    r.sh[0] = s3 * x;
    r.sh[1] = s3 * y;
    r.sh[2] = s3 * z;
    r.sh[3] = s15 * x * y;
    r.sh[4] = s15 * y * z;
    r.sh[5] = 0.5f * s5 * (3.0f * z * z - 1.0f);
    r.sh[6] = s15 * x * z;
    r.sh[7] = 0.5f * s15 * (x * x - y * y);
    int p = atomicAdd(&cursor[dst[e]], 1);
    rec[p] = r;
}

// ---------- x init ----------
__global__ __launch_bounds__(128) void k_initx(const int* __restrict__ z,
                                               const float* __restrict__ mask,
                                               const float* __restrict__ zemb,
                                               const float* __restrict__ Win,
                                               float* __restrict__ x) {
    int n = blockIdx.x;
    __shared__ float zf[M0];
    int zi = z[n];
    for (int k = threadIdx.x; k < M0; k += blockDim.x) zf[k] = zemb[zi * M0 + k];
    __syncthreads();
    int j = threadIdx.x;
    float acc = 0.0f;
    for (int k = 0; k < M0; ++k) acc += zf[k] * Win[k * M0 + j];
    float fm = mask[n];
    x[(size_t)n * DIMN + j] = acc * fm;
    for (int t = M0 + j; t < DIMN; t += M0) x[(size_t)n * DIMN + t] = 0.0f;
}

// ---------- r-table as interp pairs: rtabI[b][t][c] = (r(t,c), r(t+1,c)) ----------
__global__ __launch_bounds__(256) void k_rtab(const float* __restrict__ rW1,
                                              const float* __restrict__ rb1,
                                              const float* __restrict__ rW2,
                                              const float* __restrict__ rb2,
                                              float2* __restrict__ rtabI) {
    int blk = blockIdx.x;              // 0 .. NBLK*(NT/TCHUNK)-1
    int b = blk / (NT / TCHUNK);
    int t0 = (blk % (NT / TCHUNK)) * TCHUNK;
    int tid = threadIdx.x;
    __shared__ float rbf_s[TCHUNK][RBFD];
    __shared__ float hh_s[64][TCHUNK];   // transposed: [k][t]

    // phase A: rbf tile
    const float wdt = FCUT / (float)(RBFD - 1);
    for (int idx = tid; idx < TCHUNK * RBFD; idx += 256) {
        int tt = idx >> 5, k = idx & 31;
        float len = (float)(t0 + tt) * (FCUT / (float)(NT - 1));
        float d0 = (len - (float)k * wdt) / wdt;
        rbf_s[tt][k] = expf(-0.5f * d0 * d0);
    }
    __syncthreads();
    // phase B: h = silu(rbf @ W1 + b1), stored transposed
    const float* W1 = rW1 + b * RBFD * 64;
    for (int idx = tid; idx < TCHUNK * 64; idx += 256) {
        int tt = idx >> 6, jj = idx & 63;
        float a = rb1[b * 64 + jj];
        #pragma unroll 8
        for (int k = 0; k < RBFD; ++k) a += rbf_s[tt][k] * W1[k * 64 + jj];
        hh_s[jj][tt] = a / (1.0f + expf(-a));
    }
    __syncthreads();
    // phase C: r[t][c] = h[t] @ W2[:,c] + b2[c], 8 t per thread, c = tid (<192)
    if (tid < 192) {
        int c = tid;
        const float* W2 = rW2 + b * 64 * 192;
        float b2 = rb2[b * 192 + c];
        float2* out = rtabI + (size_t)b * NT * 192;
        for (int g = 0; g < TCHUNK / 8; ++g) {
            float acc[8];
            #pragma unroll
            for (int u = 0; u < 8; ++u) acc[u] = b2;
            for (int k = 0; k < 64; ++k) {
                float w2 = W2[k * 192 + c];
                const float4* hp = (const float4*)&hh_s[k][g * 8];
                float4 h0 = hp[0], h1 = hp[1];
                acc[0] += h0.x * w2; acc[1] += h0.y * w2;
                acc[2] += h0.z * w2; acc[3] += h0.w * w2;
                acc[4] += h1.x * w2; acc[5] += h1.y * w2;
                acc[6] += h1.z * w2; acc[7] += h1.w * w2;
            }
            #pragma unroll
            for (int u = 0; u < 8; ++u) {
                int t = t0 + g * 8 + u;
                out[(size_t)t * 192 + c].x = acc[u];
                if (t > 0) out[(size_t)(t - 1) * 192 + c].y = acc[u];
            }
        }
    }
}

// ---------- node projection: P = x[:, :128] @ Wp[b] ----------
__global__ __launch_bounds__(192) void k_proj(const float* __restrict__ x,
                                              const float* __restrict__ Wp,
                                              float* __restrict__ P) {
    int n = blockIdx.x;
    __shared__ float s[M0];
    for (int k = threadIdx.x; k < M0; k += blockDim.x) s[k] = x[(size_t)n * DIMN + k];
    __syncthreads();
    int j = threadIdx.x;   // 0..191
    float acc = 0.0f;
    for (int k = 0; k < M0; ++k) acc += s[k] * Wp[k * 192 + j];
    P[(size_t)n * 192 + j] = acc;
}

// ---------- per-node gather: msum[n][576] plane-major, 2 waves/node ----------
struct Rows { float2 ra, rb, rc; float pa, pb, pc; };

__global__ __launch_bounds__(128) void k_gather(const float* __restrict__ P,
                                                const float2* __restrict__ rt,
                                                const ERec* __restrict__ rec,
                                                const int* __restrict__ offs,
                                                float* __restrict__ msum) {
    int n = blockIdx.x;
    int t = threadIdx.x;
    int w = t >> 6;
    int j = t & 63;
    int e0 = offs[n], e1 = offs[n + 1];
    int base = e0 + w;                 // stride 2 across the 2 waves
    int nIter = (e1 - base + 1) >> 1;  // ceil((e1-base)/2), <=0 -> 0

    float m0 = 0.0f;
    float m1a[3] = {0, 0, 0};
    float m2a[5] = {0, 0, 0, 0, 0};

    if (nIter > 0) {
        const float4* RP = (const float4*)rec;
        auto ld = [&](int k) -> int { int i = base + (k << 1); return i < e1 ? i : (e1 - 1); };
        int i0 = 3 * ld(0), i1 = 3 * ld(1), i2 = 3 * ld(2);
        float4 A0 = RP[i0], A1 = RP[i0 + 1], A2 = RP[i0 + 2];
        float4 B0 = RP[i1], B1 = RP[i1 + 1], B2 = RP[i1 + 2];
        float4 C0 = RP[i2], C1 = RP[i2 + 1], C2 = RP[i2 + 2];

        Rows W0, W1;
        {
            int src = __float_as_int(A0.x), ti = __float_as_int(A0.y);
            const float2* r = rt + (size_t)ti * 192;
            W0.ra = r[j]; W0.rb = r[64 + j]; W0.rc = r[128 + j];
            const float* Ps = P + (size_t)src * 192;
            W0.pa = Ps[j]; W0.pb = Ps[64 + j]; W0.pc = Ps[128 + j];
        }
        {
            int src = __float_as_int(B0.x), ti = __float_as_int(B0.y);
            const float2* r = rt + (size_t)ti * 192;
            W1.ra = r[j]; W1.rb = r[64 + j]; W1.rc = r[128 + j];
            const float* Ps = P + (size_t)src * 192;
            W1.pa = Ps[j]; W1.pb = Ps[64 + j]; W1.pc = Ps[128 + j];
        }

        for (int k = 0; k < nIter; ++k) {
            // prefetch rec 3 ahead
            int ip = 3 * ld(k + 3);
            float4 D0 = RP[ip], D1 = RP[ip + 1], D2 = RP[ip + 2];
            // issue rows for iter k+2 (rec C arrived 2 iters ago)
            Rows W2;
            {
                int src = __float_as_int(C0.x), ti = __float_as_int(C0.y);
                const float2* r = rt + (size_t)ti * 192;
                W2.ra = r[j]; W2.rb = r[64 + j]; W2.rc = r[128 + j];
                const float* Ps = P + (size_t)src * 192;
                W2.pa = Ps[j]; W2.pb = Ps[64 + j]; W2.pc = Ps[128 + j];
            }
            // consume iter k (A, W0)
            float fr = A0.z, fc = A0.w;
            float va = W0.ra.x + fr * (W0.ra.y - W0.ra.x);
            float w0 = W0.pa * va * fc;
            m0 += w0;
            float vb = W0.rb.x + fr * (W0.rb.y - W0.rb.x);
            float w1 = W0.pb * vb * fc;
            m1a[0] += w1 * A1.x;
            m1a[1] += w1 * A1.y;
            m1a[2] += w1 * A1.z;
            float vc = W0.rc.x + fr * (W0.rc.y - W0.rc.x);
            float w2 = W0.pc * vc * fc;
            m2a[0] += w2 * A1.w;
            m2a[1] += w2 * A2.x;
            m2a[2] += w2 * A2.y;
            m2a[3] += w2 * A2.z;
            m2a[4] += w2 * A2.w;

            A0 = B0; A1 = B1; A2 = B2;
            B0 = C0; B1 = C1; B2 = C2;
            C0 = D0; C1 = D1; C2 = D2;
            W0 = W1; W1 = W2;
        }
    }

    __shared__ float mbuf[2][576];
    mbuf[w][j] = m0;
    #pragma unroll
    for (int d = 0; d < 3; ++d) mbuf[w][64 + d * 64 + j] = m1a[d];
    #pragma unroll
    for (int d = 0; d < 5; ++d) mbuf[w][256 + d * 64 + j] = m2a[d];
    __syncthreads();
    for (int c = t; c < 576; c += 128)
        msum[(size_t)n * 576 + c] = mbuf[0][c] + mbuf[1][c];
}

// ---------- output GEMM: x += res * (msum @ blockdiag(Wo)), Wo cols in VGPRs ----------
__global__ __launch_bounds__(512) void k_out(const float* __restrict__ msum,
                                             const float* __restrict__ Wo0,
                                             const float* __restrict__ Wo1,
                                             const float* __restrict__ Wo2,
                                             const float* __restrict__ res_scale, int b,
                                             float* __restrict__ x) {
    int o = threadIdx.x;
    int n0 = blockIdx.x * NPB;
    float wcol[64];
    int mbase = 0;
    if (o < 128) {
        #pragma unroll 8
        for (int c = 0; c < 64; ++c) wcol[c] = Wo0[c * M0 + o];
        mbase = 0;
    } else if (o < 320) {
        int q = o - 128, k = q / 3, d = q - 3 * k;
        #pragma unroll 8
        for (int c = 0; c < 64; ++c) wcol[c] = Wo1[c * M1 + k];
        mbase = 64 + d * 64;
    } else if (o < 480) {
        int q = o - 320, k = q / 5, d = q - 5 * k;
        #pragma unroll 8
        for (int c = 0; c < 64; ++c) wcol[c] = Wo2[c * M2 + k];
        mbase = 256 + d * 64;
    }
    __shared__ float ms[576];
    float rs = res_scale[b];
    for (int u = 0; u < NPB; ++u) {
        int n = n0 + u;
        for (int i = threadIdx.x; i < 576; i += 512) ms[i] = msum[(size_t)n * 576 + i];
        __syncthreads();
        if (o < 480) {
            const float4* mp = (const float4*)(ms + mbase);
            float acc = 0.0f;
            #pragma unroll
            for (int c4 = 0; c4 < 16; ++c4) {
                float4 m4 = mp[c4];
                acc += wcol[4 * c4 + 0] * m4.x + wcol[4 * c4 + 1] * m4.y +
                       wcol[4 * c4 + 2] * m4.z + wcol[4 * c4 + 3] * m4.w;
            }
            x[(size_t)n * DIMN + o] += rs * acc;
        }
        __syncthreads();
    }
}

// ---------- final irrep norm + mask ----------
__global__ __launch_bounds__(64) void k_norm(const float* __restrict__ x,
                                             const float* __restrict__ mask,
                                             float* __restrict__ out) {
    int n = blockIdx.x;
    int j = threadIdx.x;
    const float* xn = x + (size_t)n * DIMN;
    float s0 = 0, s1 = 0, s2 = 0;
    for (int c = j; c < 128; c += 64) { float v = xn[c]; s0 += v * v; }
    for (int c = j; c < 192; c += 64) { float v = xn[128 + c]; s1 += v * v; }
    for (int c = j; c < 160; c += 64) { float v = xn[320 + c]; s2 += v * v; }
    for (int d = 32; d > 0; d >>= 1) {
        s0 += __shfl_down(s0, d);
        s1 += __shfl_down(s1, d);
        s2 += __shfl_down(s2, d);
    }
    __shared__ float inv0, inv1, inv2;
    if (j == 0) {
        inv0 = rsqrtf(s0 / (float)M0 + 1e-6f);
        inv1 = rsqrtf(s1 / (float)M1 + 1e-6f);
        inv2 = rsqrtf(s2 / (float)M2 + 1e-6f);
    }
    __syncthreads();
    float fm = mask[n];
    float* on = out + (size_t)n * DIMN;
    for (int c = j; c < 128; c += 64) on[c] = xn[c] * inv0 * fm;
    for (int c = j; c < 192; c += 64) on[128 + c] = xn[128 + c] * inv1 * fm;
    for (int c = j; c < 160; c += 64) on[320 + c] = xn[320 + c] * inv2 * fm;
}

extern "C" void kernel_launch(void* const* d_in, const int* in_sizes, int n_in,
                              void* d_out, int out_size, void* d_ws, size_t ws_size,
                              hipStream_t stream) {
    const int*   z    = (const int*)d_in[0];
    const float* mask = (const float*)d_in[1];
    const int*   esrc = (const int*)d_in[2];
    const int*   edst = (const int*)d_in[3];
    const float* ew   = (const float*)d_in[4];
    const float* ev   = (const float*)d_in[5];
    const float* zemb = (const float*)d_in[6];
    const float* Win  = (const float*)d_in[7];
    const float* Wp   = (const float*)d_in[8];
    const float* rW1  = (const float*)d_in[9];
    const float* rb1  = (const float*)d_in[10];
    const float* rW2  = (const float*)d_in[11];
    const float* rb2  = (const float*)d_in[12];
    const float* Wo0  = (const float*)d_in[13];
    const float* Wo1  = (const float*)d_in[14];
    const float* Wo2  = (const float*)d_in[15];
    const float* res  = (const float*)d_in[16];

    const int BN = in_sizes[0];      // 4096
    const int E  = in_sizes[2];      // 131072

    // ---- workspace carve ----
    char* w = (char*)d_ws;
    float*  x     = (float*)w;  w += (size_t)BN * DIMN * 4;            // 7.86 MB
    float*  P     = (float*)w;  w += (size_t)BN * 192 * 4;             // 3.15 MB
    float2* rtabI = (float2*)w; w += (size_t)NBLK * NT * 192 * 8;      // 9.44 MB
    ERec*   rec   = (ERec*)w;   w += (size_t)E * sizeof(ERec);         // 6.29 MB
    float*  msum  = (float*)w;  w += (size_t)BN * 576 * 4;             // 9.44 MB
    int* counts = (int*)w;   w += (size_t)BN * 4;
    int* offs   = (int*)w;   w += (size_t)(BN + 4) * 4;
    int* cursor = (int*)w;   w += (size_t)BN * 4;

    hipMemsetAsync(counts, 0, (size_t)BN * 4, stream);

    k_count<<<(E + 255) / 256, 256, 0, stream>>>(edst, counts, E);
    k_scan<<<1, 1024, 0, stream>>>(counts, offs, cursor, BN);
    k_build<<<(E + 255) / 256, 256, 0, stream>>>(ew, ev, esrc, edst, cursor, rec, E);
    k_initx<<<BN, 128, 0, stream>>>(z, mask, zemb, Win, x);
    k_rtab<<<NBLK * (NT / TCHUNK), 256, 0, stream>>>(rW1, rb1, rW2, rb2, rtabI);

    for (int b = 0; b < NBLK; ++b) {
        k_proj<<<BN, 192, 0, stream>>>(x, Wp + (size_t)b * M0 * 192, P);
        k_gather<<<BN, 128, 0, stream>>>(P, rtabI + (size_t)b * NT * 192, rec, offs, msum);
        k_out<<<BN / NPB, 512, 0, stream>>>(msum,
                                            Wo0 + (size_t)b * MSGC * M0,
                                            Wo1 + (size_t)b * MSGC * M1,
                                            Wo2 + (size_t)b * MSGC * M2,
                                            res, b, x);
    }

    k_norm<<<BN, 64, 0, stream>>>(x, mask, (float*)d_out);
}

// Round 4
// 316.695 us; speedup vs baseline: 1.4917x; 1.4917x over previous
//
#include <hip/hip_runtime.h>
#include <math.h>

#define M0 128
#define M1 64
#define M2 32
#define DIMN 480      // 128 + 3*64 + 5*32
#define MSGC 64
#define NBLK 3
#define RBFD 32
#define NT 2048       // r-table resolution
#define TCHUNK 32     // t-values per k_rtab block
#define NPB 8         // nodes per k_out block
#define FCUT 5.0f

// 48-byte dst-sorted edge record
struct __align__(16) ERec {
    int   src;
    int   ti;
    float fr;
    float fc;
    float sh[8];   // sh1..sh8
};

// ---------- pass 1: count edges per dst ----------
__global__ void k_count(const int* __restrict__ dst, int* __restrict__ counts, int E) {
    int e = blockIdx.x * blockDim.x + threadIdx.x;
    if (e >= E) return;
    atomicAdd(&counts[dst[e]], 1);
}

// ---------- exclusive prefix scan of counts (single block) ----------
__global__ void k_scan(const int* __restrict__ counts, int* __restrict__ offs,
                       int* __restrict__ cursor, int n) {
    __shared__ int buf[4096];
    for (int i = threadIdx.x; i < n; i += blockDim.x) buf[i] = counts[i];
    __syncthreads();
    for (int d = 1; d < n; d <<= 1) {
        int vals[4];
        int k = 0;
        for (int i = threadIdx.x; i < n; i += blockDim.x, ++k)
            vals[k] = (i >= d) ? buf[i - d] : 0;
        __syncthreads();
        k = 0;
        for (int i = threadIdx.x; i < n; i += blockDim.x, ++k)
            buf[i] += vals[k];
        __syncthreads();
    }
    for (int i = threadIdx.x; i < n; i += blockDim.x) {
        int excl = (i == 0) ? 0 : buf[i - 1];
        offs[i] = excl;
        cursor[i] = excl;
    }
    if (threadIdx.x == 0) offs[n] = buf[n - 1];
}

// ---------- pass 2: edge features scattered into dst order ----------
__global__ void k_build(const float* __restrict__ ew, const float* __restrict__ ev,
                        const int* __restrict__ src, const int* __restrict__ dst,
                        int* __restrict__ cursor, ERec* __restrict__ rec, int E) {
    int e = blockIdx.x * blockDim.x + threadIdx.x;
    if (e >= E) return;
    float len = ew[e];
    float inv = 1.0f / fmaxf(len, 1e-8f);
    float x = ev[e * 3 + 0] * inv;
    float y = ev[e * 3 + 1] * inv;
    float z = ev[e * 3 + 2] * inv;
    const float s3 = 1.7320508075688772f, s5 = 2.23606797749979f, s15 = 3.872983346207417f;
    ERec r;
    r.src = src[e];
    float u = fminf(len, FCUT) * ((float)(NT - 1) / FCUT);
    int ti = (int)u;
    ti = min(ti, NT - 2);
    r.ti = ti;
    r.fr = u - (float)ti;
    float t = fminf(len / FCUT, 1.0f);
    r.fc = 0.5f * (cosf(3.14159265358979323846f * t) + 1.0f);
    r.sh[0] = s3 * x;
    r.sh[1] = s3 * y;
    r.sh[2] = s3 * z;
    r.sh[3] = s15 * x * y;
    r.sh[4] = s15 * y * z;
    r.sh[5] = 0.5f * s5 * (3.0f * z * z - 1.0f);
    r.sh[6] = s15 * x * z;
    r.sh[7] = 0.5f * s15 * (x * x - y * y);
    int p = atomicAdd(&cursor[dst[e]], 1);
    rec[p] = r;
}

// ---------- x init ----------
__global__ __launch_bounds__(128) void k_initx(const int* __restrict__ z,
                                               const float* __restrict__ mask,
                                               const float* __restrict__ zemb,
                                               const float* __restrict__ Win,
                                               float* __restrict__ x) {
    int n = blockIdx.x;
    __shared__ float zf[M0];
    int zi = z[n];
    for (int k = threadIdx.x; k < M0; k += blockDim.x) zf[k] = zemb[zi * M0 + k];
    __syncthreads();
    int j = threadIdx.x;
    float acc = 0.0f;
    for (int k = 0; k < M0; ++k) acc += zf[k] * Win[k * M0 + j];
    float fm = mask[n];
    x[(size_t)n * DIMN + j] = acc * fm;
    for (int t = M0 + j; t < DIMN; t += M0) x[(size_t)n * DIMN + t] = 0.0f;
}

// ---------- r-table as interp pairs: rtabI[b][t][c] = (r(t,c), r(t+1,c)) ----------
__global__ __launch_bounds__(256) void k_rtab(const float* __restrict__ rW1,
                                              const float* __restrict__ rb1,
                                              const float* __restrict__ rW2,
                                              const float* __restrict__ rb2,
                                              float2* __restrict__ rtabI) {
    int blk = blockIdx.x;              // 0 .. NBLK*(NT/TCHUNK)-1
    int b = blk / (NT / TCHUNK);
    int t0 = (blk % (NT / TCHUNK)) * TCHUNK;
    int tid = threadIdx.x;
    __shared__ float rbf_s[TCHUNK][RBFD];
    __shared__ float hh_s[64][TCHUNK];   // transposed: [k][t]

    // phase A: rbf tile
    const float wdt = FCUT / (float)(RBFD - 1);
    for (int idx = tid; idx < TCHUNK * RBFD; idx += 256) {
        int tt = idx >> 5, k = idx & 31;
        float len = (float)(t0 + tt) * (FCUT / (float)(NT - 1));
        float d0 = (len - (float)k * wdt) / wdt;
        rbf_s[tt][k] = expf(-0.5f * d0 * d0);
    }
    __syncthreads();
    // phase B: h = silu(rbf @ W1 + b1), stored transposed
    const float* W1 = rW1 + b * RBFD * 64;
    for (int idx = tid; idx < TCHUNK * 64; idx += 256) {
        int tt = idx >> 6, jj = idx & 63;
        float a = rb1[b * 64 + jj];
        #pragma unroll 8
        for (int k = 0; k < RBFD; ++k) a += rbf_s[tt][k] * W1[k * 64 + jj];
        hh_s[jj][tt] = a / (1.0f + expf(-a));
    }
    __syncthreads();
    // phase C: r[t][c] = h[t] @ W2[:,c] + b2[c], 8 t per thread, c = tid (<192)
    if (tid < 192) {
        int c = tid;
        const float* W2 = rW2 + b * 64 * 192;
        float b2 = rb2[b * 192 + c];
        float2* out = rtabI + (size_t)b * NT * 192;
        for (int g = 0; g < TCHUNK / 8; ++g) {
            float acc[8];
            #pragma unroll
            for (int u = 0; u < 8; ++u) acc[u] = b2;
            for (int k = 0; k < 64; ++k) {
                float w2 = W2[k * 192 + c];
                const float4* hp = (const float4*)&hh_s[k][g * 8];
                float4 h0 = hp[0], h1 = hp[1];
                acc[0] += h0.x * w2; acc[1] += h0.y * w2;
                acc[2] += h0.z * w2; acc[3] += h0.w * w2;
                acc[4] += h1.x * w2; acc[5] += h1.y * w2;
                acc[6] += h1.z * w2; acc[7] += h1.w * w2;
            }
            #pragma unroll
            for (int u = 0; u < 8; ++u) {
                int t = t0 + g * 8 + u;
                out[(size_t)t * 192 + c].x = acc[u];
                if (t > 0) out[(size_t)(t - 1) * 192 + c].y = acc[u];
            }
        }
    }
}

// ---------- node projection: P = x[:, :128] @ Wp[b] ----------
__global__ __launch_bounds__(192) void k_proj(const float* __restrict__ x,
                                              const float* __restrict__ Wp,
                                              float* __restrict__ P) {
    int n = blockIdx.x;
    __shared__ float s[M0];
    for (int k = threadIdx.x; k < M0; k += blockDim.x) s[k] = x[(size_t)n * DIMN + k];
    __syncthreads();
    int j = threadIdx.x;   // 0..191
    float acc = 0.0f;
    for (int k = 0; k < M0; ++k) acc += s[k] * Wp[k * 192 + j];
    P[(size_t)n * 192 + j] = acc;
}

// ---------- per-node gather: msum[n][576] plane-major, 2 waves/node ----------
struct Rows { float2 ra, rb, rc; float pa, pb, pc; };

__global__ __launch_bounds__(128) void k_gather(const float* __restrict__ P,
                                                const float2* __restrict__ rt,
                                                const ERec* __restrict__ rec,
                                                const int* __restrict__ offs,
                                                float* __restrict__ msum) {
    int n = blockIdx.x;
    int t = threadIdx.x;
    int w = t >> 6;
    int j = t & 63;
    int e0 = offs[n], e1 = offs[n + 1];
    int base = e0 + w;                 // stride 2 across the 2 waves
    int nIter = (e1 - base + 1) >> 1;  // ceil((e1-base)/2), <=0 -> 0

    float m0 = 0.0f;
    float m1a[3] = {0, 0, 0};
    float m2a[5] = {0, 0, 0, 0, 0};

    if (nIter > 0) {
        const float4* RP = (const float4*)rec;
        auto ld = [&](int k) -> int { int i = base + (k << 1); return i < e1 ? i : (e1 - 1); };
        int i0 = 3 * ld(0), i1 = 3 * ld(1), i2 = 3 * ld(2);
        float4 A0 = RP[i0], A1 = RP[i0 + 1], A2 = RP[i0 + 2];
        float4 B0 = RP[i1], B1 = RP[i1 + 1], B2 = RP[i1 + 2];
        float4 C0 = RP[i2], C1 = RP[i2 + 1], C2 = RP[i2 + 2];

        Rows W0, W1;
        {
            int src = __float_as_int(A0.x), ti = __float_as_int(A0.y);
            const float2* r = rt + (size_t)ti * 192;
            W0.ra = r[j]; W0.rb = r[64 + j]; W0.rc = r[128 + j];
            const float* Ps = P + (size_t)src * 192;
            W0.pa = Ps[j]; W0.pb = Ps[64 + j]; W0.pc = Ps[128 + j];
        }
        {
            int src = __float_as_int(B0.x), ti = __float_as_int(B0.y);
            const float2* r = rt + (size_t)ti * 192;
            W1.ra = r[j]; W1.rb = r[64 + j]; W1.rc = r[128 + j];
            const float* Ps = P + (size_t)src * 192;
            W1.pa = Ps[j]; W1.pb = Ps[64 + j]; W1.pc = Ps[128 + j];
        }

        for (int k = 0; k < nIter; ++k) {
            // prefetch rec 3 ahead
            int ip = 3 * ld(k + 3);
            float4 D0 = RP[ip], D1 = RP[ip + 1], D2 = RP[ip + 2];
            // issue rows for iter k+2 (rec C arrived 2 iters ago)
            Rows W2;
            {
                int src = __float_as_int(C0.x), ti = __float_as_int(C0.y);
                const float2* r = rt + (size_t)ti * 192;
                W2.ra = r[j]; W2.rb = r[64 + j]; W2.rc = r[128 + j];
                const float* Ps = P + (size_t)src * 192;
                W2.pa = Ps[j]; W2.pb = Ps[64 + j]; W2.pc = Ps[128 + j];
            }
            // consume iter k (A, W0)
            float fr = A0.z, fc = A0.w;
            float va = W0.ra.x + fr * (W0.ra.y - W0.ra.x);
            float w0 = W0.pa * va * fc;
            m0 += w0;
            float vb = W0.rb.x + fr * (W0.rb.y - W0.rb.x);
            float w1 = W0.pb * vb * fc;
            m1a[0] += w1 * A1.x;
            m1a[1] += w1 * A1.y;
            m1a[2] += w1 * A1.z;
            float vc = W0.rc.x + fr * (W0.rc.y - W0.rc.x);
            float w2 = W0.pc * vc * fc;
            m2a[0] += w2 * A1.w;
            m2a[1] += w2 * A2.x;
            m2a[2] += w2 * A2.y;
            m2a[3] += w2 * A2.z;
            m2a[4] += w2 * A2.w;

            A0 = B0; A1 = B1; A2 = B2;
            B0 = C0; B1 = C1; B2 = C2;
            C0 = D0; C1 = D1; C2 = D2;
            W0 = W1; W1 = W2;
        }
    }

    __shared__ float mbuf[2][576];
    mbuf[w][j] = m0;
    #pragma unroll
    for (int d = 0; d < 3; ++d) mbuf[w][64 + d * 64 + j] = m1a[d];
    #pragma unroll
    for (int d = 0; d < 5; ++d) mbuf[w][256 + d * 64 + j] = m2a[d];
    __syncthreads();
    for (int c = t; c < 576; c += 128)
        msum[(size_t)n * 576 + c] = mbuf[0][c] + mbuf[1][c];
}

// ---------- output transform: x += res * (msum @ blockdiag(Wo)) ----------
// acc[NPB] in registers (static indices only); Wo read coalesced from global
// (L1/L2-resident, 56 KB); ms[] LDS reads are wave-broadcast (conflict-free).
__global__ __launch_bounds__(512, 2) void k_out(const float* __restrict__ msum,
                                                const float* __restrict__ Wo0,
                                                const float* __restrict__ Wo1,
                                                const float* __restrict__ Wo2,
                                                const float* __restrict__ res_scale, int b,
                                                float* __restrict__ x) {
    int o = threadIdx.x;           // 0..511 (only o<480 compute)
    int n0 = blockIdx.x * NPB;
    __shared__ float ms[NPB][576];

    const float4* srcv = (const float4*)(msum + (size_t)n0 * 576);
    float4* dstv = (float4*)&ms[0][0];
    for (int i = threadIdx.x; i < NPB * 576 / 4; i += 512) dstv[i] = srcv[i];
    __syncthreads();

    if (o < DIMN) {
        const float* W;
        int stride, mbase;
        if (o < M0) {
            W = Wo0 + o; stride = M0; mbase = 0;
        } else if (o < M0 + 3 * M1) {
            int q = o - M0, k = q / 3, d = q - 3 * k;
            W = Wo1 + k; stride = M1; mbase = 64 + d * 64;
        } else {
            int q = o - (M0 + 3 * M1), k = q / 5, d = q - 5 * k;
            W = Wo2 + k; stride = M2; mbase = 256 + d * 64;
        }
        float acc[NPB];
        #pragma unroll
        for (int u = 0; u < NPB; ++u) acc[u] = 0.0f;
        for (int c = 0; c < 64; ++c) {
            float wv = W[c * stride];
            float* msc = &ms[0][mbase + c];
            #pragma unroll
            for (int u = 0; u < NPB; ++u) acc[u] += msc[u * 576] * wv;
        }
        float rs = res_scale[b];
        #pragma unroll
        for (int u = 0; u < NPB; ++u)
            x[(size_t)(n0 + u) * DIMN + o] += rs * acc[u];
    }
}

// ---------- final irrep norm + mask ----------
__global__ __launch_bounds__(64) void k_norm(const float* __restrict__ x,
                                             const float* __restrict__ mask,
                                             float* __restrict__ out) {
    int n = blockIdx.x;
    int j = threadIdx.x;
    const float* xn = x + (size_t)n * DIMN;
    float s0 = 0, s1 = 0, s2 = 0;
    for (int c = j; c < 128; c += 64) { float v = xn[c]; s0 += v * v; }
    for (int c = j; c < 192; c += 64) { float v = xn[128 + c]; s1 += v * v; }
    for (int c = j; c < 160; c += 64) { float v = xn[320 + c]; s2 += v * v; }
    for (int d = 32; d > 0; d >>= 1) {
        s0 += __shfl_down(s0, d);
        s1 += __shfl_down(s1, d);
        s2 += __shfl_down(s2, d);
    }
    __shared__ float inv0, inv1, inv2;
    if (j == 0) {
        inv0 = rsqrtf(s0 / (float)M0 + 1e-6f);
        inv1 = rsqrtf(s1 / (float)M1 + 1e-6f);
        inv2 = rsqrtf(s2 / (float)M2 + 1e-6f);
    }
    __syncthreads();
    float fm = mask[n];
    float* on = out + (size_t)n * DIMN;
    for (int c = j; c < 128; c += 64) on[c] = xn[c] * inv0 * fm;
    for (int c = j; c < 192; c += 64) on[128 + c] = xn[128 + c] * inv1 * fm;
    for (int c = j; c < 160; c += 64) on[320 + c] = xn[320 + c] * inv2 * fm;
}

extern "C" void kernel_launch(void* const* d_in, const int* in_sizes, int n_in,
                              void* d_out, int out_size, void* d_ws, size_t ws_size,
                              hipStream_t stream) {
    const int*   z    = (const int*)d_in[0];
    const float* mask = (const float*)d_in[1];
    const int*   esrc = (const int*)d_in[2];
    const int*   edst = (const int*)d_in[3];
    const float* ew   = (const float*)d_in[4];
    const float* ev   = (const float*)d_in[5];
    const float* zemb = (const float*)d_in[6];
    const float* Win  = (const float*)d_in[7];
    const float* Wp   = (const float*)d_in[8];
    const float* rW1  = (const float*)d_in[9];
    const float* rb1  = (const float*)d_in[10];
    const float* rW2  = (const float*)d_in[11];
    const float* rb2  = (const float*)d_in[12];
    const float* Wo0  = (const float*)d_in[13];
    const float* Wo1  = (const float*)d_in[14];
    const float* Wo2  = (const float*)d_in[15];
    const float* res  = (const float*)d_in[16];

    const int BN = in_sizes[0];      // 4096
    const int E  = in_sizes[2];      // 131072

    // ---- workspace carve ----
    char* w = (char*)d_ws;
    float*  x     = (float*)w;  w += (size_t)BN * DIMN * 4;            // 7.86 MB
    float*  P     = (float*)w;  w += (size_t)BN * 192 * 4;             // 3.15 MB
    float2* rtabI = (float2*)w; w += (size_t)NBLK * NT * 192 * 8;      // 9.44 MB
    ERec*   rec   = (ERec*)w;   w += (size_t)E * sizeof(ERec);         // 6.29 MB
    float*  msum  = (float*)w;  w += (size_t)BN * 576 * 4;             // 9.44 MB
    int* counts = (int*)w;   w += (size_t)BN * 4;
    int* offs   = (int*)w;   w += (size_t)(BN + 4) * 4;
    int* cursor = (int*)w;   w += (size_t)BN * 4;

    hipMemsetAsync(counts, 0, (size_t)BN * 4, stream);

    k_count<<<(E + 255) / 256, 256, 0, stream>>>(edst, counts, E);
    k_scan<<<1, 1024, 0, stream>>>(counts, offs, cursor, BN);
    k_build<<<(E + 255) / 256, 256, 0, stream>>>(ew, ev, esrc, edst, cursor, rec, E);
    k_initx<<<BN, 128, 0, stream>>>(z, mask, zemb, Win, x);
    k_rtab<<<NBLK * (NT / TCHUNK), 256, 0, stream>>>(rW1, rb1, rW2, rb2, rtabI);

    for (int b = 0; b < NBLK; ++b) {
        k_proj<<<BN, 192, 0, stream>>>(x, Wp + (size_t)b * M0 * 192, P);
        k_gather<<<BN, 128, 0, stream>>>(P, rtabI + (size_t)b * NT * 192, rec, offs, msum);
        k_out<<<BN / NPB, 512, 0, stream>>>(msum,
                                            Wo0 + (size_t)b * MSGC * M0,
                                            Wo1 + (size_t)b * MSGC * M1,
                                            Wo2 + (size_t)b * MSGC * M2,
                                            res, b, x);
    }

    k_norm<<<BN, 64, 0, stream>>>(x, mask, (float*)d_out);
}

// Round 5
// 288.727 us; speedup vs baseline: 1.6362x; 1.0969x over previous
//
#include <hip/hip_runtime.h>
#include <math.h>

#define M0 128
#define M1 64
#define M2 32
#define DIMN 480      // 128 + 3*64 + 5*32
#define MSGC 64
#define NBLK 3
#define RBFD 32
#define NT 2048       // r-table resolution
#define TCHUNK 32     // t-values per k_rtab block
#define NPB 8         // nodes per k_out block
#define NNP 16        // nodes per k_proj block
#define FCUT 5.0f

typedef unsigned int  u32;
typedef unsigned short u16;

__device__ __forceinline__ u16 f2bf(float f) {
    u32 u = __float_as_uint(f);
    u32 r = (u + 0x7fffu + ((u >> 16) & 1u)) >> 16;
    return (u16)r;
}
__device__ __forceinline__ float bf_lo(u32 v) { return __uint_as_float(v << 16); }
__device__ __forceinline__ float bf_hi(u32 v) { return __uint_as_float(v & 0xffff0000u); }
__device__ __forceinline__ float bf2f(u32 us) { return __uint_as_float(us << 16); }

// 48-byte dst-sorted edge record
struct __align__(16) ERec {
    int   src;
    int   ti;
    float fr;
    float fc;
    float sh[8];   // sh1..sh8
};

// ---------- zero counts (replaces pathologically slow rocclr fill) ----------
__global__ void k_zero(int* __restrict__ p, int n) {
    int i = blockIdx.x * blockDim.x + threadIdx.x;
    if (i < n) p[i] = 0;
}

// ---------- pass 1: count edges per dst ----------
__global__ void k_count(const int* __restrict__ dst, int* __restrict__ counts, int E) {
    int e = blockIdx.x * blockDim.x + threadIdx.x;
    if (e >= E) return;
    atomicAdd(&counts[dst[e]], 1);
}

// ---------- exclusive prefix scan of counts (single block) ----------
__global__ void k_scan(const int* __restrict__ counts, int* __restrict__ offs,
                       int* __restrict__ cursor, int n) {
    __shared__ int buf[4096];
    for (int i = threadIdx.x; i < n; i += blockDim.x) buf[i] = counts[i];
    __syncthreads();
    for (int d = 1; d < n; d <<= 1) {
        int vals[4];
        int k = 0;
        for (int i = threadIdx.x; i < n; i += blockDim.x, ++k)
            vals[k] = (i >= d) ? buf[i - d] : 0;
        __syncthreads();
        k = 0;
        for (int i = threadIdx.x; i < n; i += blockDim.x, ++k)
            buf[i] += vals[k];
        __syncthreads();
    }
    for (int i = threadIdx.x; i < n; i += blockDim.x) {
        int excl = (i == 0) ? 0 : buf[i - 1];
        offs[i] = excl;
        cursor[i] = excl;
    }
    if (threadIdx.x == 0) offs[n] = buf[n - 1];
}

// ---------- pass 2: edge features scattered into dst order ----------
__global__ void k_build(const float* __restrict__ ew, const float* __restrict__ ev,
                        const int* __restrict__ src, const int* __restrict__ dst,
                        int* __restrict__ cursor, ERec* __restrict__ rec, int E) {
    int e = blockIdx.x * blockDim.x + threadIdx.x;
    if (e >= E) return;
    float len = ew[e];
    float inv = 1.0f / fmaxf(len, 1e-8f);
    float x = ev[e * 3 + 0] * inv;
    float y = ev[e * 3 + 1] * inv;
    float z = ev[e * 3 + 2] * inv;
    const float s3 = 1.7320508075688772f, s5 = 2.23606797749979f, s15 = 3.872983346207417f;
    ERec r;
    r.src = src[e];
    float u = fminf(len, FCUT) * ((float)(NT - 1) / FCUT);
    int ti = (int)u;
    ti = min(ti, NT - 2);
    r.ti = ti;
    r.fr = u - (float)ti;
    float t = fminf(len / FCUT, 1.0f);
    r.fc = 0.5f * (cosf(3.14159265358979323846f * t) + 1.0f);
    r.sh[0] = s3 * x;
    r.sh[1] = s3 * y;
    r.sh[2] = s3 * z;
    r.sh[3] = s15 * x * y;
    r.sh[4] = s15 * y * z;
    r.sh[5] = 0.5f * s5 * (3.0f * z * z - 1.0f);
    r.sh[6] = s15 * x * z;
    r.sh[7] = 0.5f * s15 * (x * x - y * y);
    int p = atomicAdd(&cursor[dst[e]], 1);
    rec[p] = r;
}

// ---------- x init ----------
__global__ __launch_bounds__(128) void k_initx(const int* __restrict__ z,
                                               const float* __restrict__ mask,
                                               const float* __restrict__ zemb,
                                               const float* __restrict__ Win,
                                               float* __restrict__ x) {
    int n = blockIdx.x;
    __shared__ float zf[M0];
    int zi = z[n];
    for (int k = threadIdx.x; k < M0; k += blockDim.x) zf[k] = zemb[zi * M0 + k];
    __syncthreads();
    int j = threadIdx.x;
    float acc = 0.0f;
    for (int k = 0; k < M0; ++k) acc += zf[k] * Win[k * M0 + j];
    float fm = mask[n];
    x[(size_t)n * DIMN + j] = acc * fm;
    for (int t = M0 + j; t < DIMN; t += M0) x[(size_t)n * DIMN + t] = 0.0f;
}

// ---------- r-table (scalar fp32): rS[b][t][c] ----------
__global__ __launch_bounds__(256) void k_rtab(const float* __restrict__ rW1,
                                              const float* __restrict__ rb1,
                                              const float* __restrict__ rW2,
                                              const float* __restrict__ rb2,
                                              float* __restrict__ rS) {
    int blk = blockIdx.x;              // 0 .. NBLK*(NT/TCHUNK)-1
    int b = blk / (NT / TCHUNK);
    int t0 = (blk % (NT / TCHUNK)) * TCHUNK;
    int tid = threadIdx.x;
    __shared__ float rbf_s[TCHUNK][RBFD];
    __shared__ float hh_s[64][TCHUNK];   // transposed: [k][t]

    const float wdt = FCUT / (float)(RBFD - 1);
    for (int idx = tid; idx < TCHUNK * RBFD; idx += 256) {
        int tt = idx >> 5, k = idx & 31;
        float len = (float)(t0 + tt) * (FCUT / (float)(NT - 1));
        float d0 = (len - (float)k * wdt) / wdt;
        rbf_s[tt][k] = expf(-0.5f * d0 * d0);
    }
    __syncthreads();
    const float* W1 = rW1 + b * RBFD * 64;
    for (int idx = tid; idx < TCHUNK * 64; idx += 256) {
        int tt = idx >> 6, jj = idx & 63;
        float a = rb1[b * 64 + jj];
        #pragma unroll 8
        for (int k = 0; k < RBFD; ++k) a += rbf_s[tt][k] * W1[k * 64 + jj];
        hh_s[jj][tt] = a / (1.0f + expf(-a));
    }
    __syncthreads();
    if (tid < 192) {
        int c = tid;
        const float* W2 = rW2 + b * 64 * 192;
        float b2 = rb2[b * 192 + c];
        float* out = rS + (size_t)b * NT * 192;
        for (int g = 0; g < TCHUNK / 8; ++g) {
            float acc[8];
            #pragma unroll
            for (int u = 0; u < 8; ++u) acc[u] = b2;
            for (int k = 0; k < 64; ++k) {
                float w2 = W2[k * 192 + c];
                const float4* hp = (const float4*)&hh_s[k][g * 8];
                float4 h0 = hp[0], h1 = hp[1];
                acc[0] += h0.x * w2; acc[1] += h0.y * w2;
                acc[2] += h0.z * w2; acc[3] += h0.w * w2;
                acc[4] += h1.x * w2; acc[5] += h1.y * w2;
                acc[6] += h1.z * w2; acc[7] += h1.w * w2;
            }
            #pragma unroll
            for (int u = 0; u < 8; ++u) {
                int t = t0 + g * 8 + u;
                out[(size_t)t * 192 + c] = acc[u];
            }
        }
    }
}

// ---------- pack r-table: rP[b][t][c] = bf16(rS[t]) | bf16(rS[t+1])<<16 ----------
__global__ void k_pack(const float* __restrict__ rS, u32* __restrict__ rP, int total) {
    int idx = blockIdx.x * blockDim.x + threadIdx.x;
    if (idx >= total) return;
    int t = (idx / 192) % NT;
    float lo = rS[idx];
    float hi = (t < NT - 1) ? rS[idx + 192] : lo;
    rP[idx] = (u32)f2bf(lo) | ((u32)f2bf(hi) << 16);
}

// ---------- node projection: P_bf = bf16(x[:, :128] @ Wp[b]), 16 nodes/block ----------
__global__ __launch_bounds__(192) void k_proj(const float* __restrict__ x,
                                              const float* __restrict__ Wp,
                                              u16* __restrict__ P) {
    int n0 = blockIdx.x * NNP;
    int j = threadIdx.x;   // 0..191
    __shared__ float xs[NNP][M0];
    for (int idx = j; idx < NNP * M0; idx += 192) {
        int n = idx >> 7, c = idx & 127;
        xs[n][c] = x[(size_t)(n0 + n) * DIMN + c];
    }
    __syncthreads();
    float acc[NNP];
    #pragma unroll
    for (int u = 0; u < NNP; ++u) acc[u] = 0.0f;
    for (int k = 0; k < M0; ++k) {
        float wv = Wp[k * 192 + j];
        #pragma unroll
        for (int u = 0; u < NNP; ++u) acc[u] += xs[u][k] * wv;
    }
    #pragma unroll
    for (int u = 0; u < NNP; ++u)
        P[(size_t)(n0 + u) * 192 + j] = f2bf(acc[u]);
}

// ---------- per-node gather: msum[n][576] plane-major, 2 waves/node ----------
struct Rows { u32 ra, rb, rc; u32 pa, pb, pc; };

__global__ __launch_bounds__(128) void k_gather(const u16* __restrict__ P,
                                                const u32* __restrict__ rt,
                                                const ERec* __restrict__ rec,
                                                const int* __restrict__ offs,
                                                float* __restrict__ msum) {
    int n = blockIdx.x;
    int t = threadIdx.x;
    int w = t >> 6;
    int j = t & 63;
    int e0 = offs[n], e1 = offs[n + 1];
    int base = e0 + w;                 // stride 2 across the 2 waves
    int nIter = (e1 - base + 1) >> 1;

    float m0 = 0.0f;
    float m1a[3] = {0, 0, 0};
    float m2a[5] = {0, 0, 0, 0, 0};

    if (nIter > 0) {
        const float4* RP = (const float4*)rec;
        auto ld = [&](int k) -> int { int i = base + (k << 1); return i < e1 ? i : (e1 - 1); };
        int i0 = 3 * ld(0), i1 = 3 * ld(1), i2 = 3 * ld(2);
        float4 A0 = RP[i0], A1 = RP[i0 + 1], A2 = RP[i0 + 2];
        float4 B0 = RP[i1], B1 = RP[i1 + 1], B2 = RP[i1 + 2];
        float4 C0 = RP[i2], C1 = RP[i2 + 1], C2 = RP[i2 + 2];

        Rows W0, W1;
        {
            int src = __float_as_int(A0.x), ti = __float_as_int(A0.y);
            const u32* r = rt + (size_t)ti * 192;
            W0.ra = r[j]; W0.rb = r[64 + j]; W0.rc = r[128 + j];
            const u16* Ps = P + (size_t)src * 192;
            W0.pa = Ps[j]; W0.pb = Ps[64 + j]; W0.pc = Ps[128 + j];
        }
        {
            int src = __float_as_int(B0.x), ti = __float_as_int(B0.y);
            const u32* r = rt + (size_t)ti * 192;
            W1.ra = r[j]; W1.rb = r[64 + j]; W1.rc = r[128 + j];
            const u16* Ps = P + (size_t)src * 192;
            W1.pa = Ps[j]; W1.pb = Ps[64 + j]; W1.pc = Ps[128 + j];
        }

        for (int k = 0; k < nIter; ++k) {
            int ip = 3 * ld(k + 3);
            float4 D0 = RP[ip], D1 = RP[ip + 1], D2 = RP[ip + 2];
            Rows W2;
            {
                int src = __float_as_int(C0.x), ti = __float_as_int(C0.y);
                const u32* r = rt + (size_t)ti * 192;
                W2.ra = r[j]; W2.rb = r[64 + j]; W2.rc = r[128 + j];
                const u16* Ps = P + (size_t)src * 192;
                W2.pa = Ps[j]; W2.pb = Ps[64 + j]; W2.pc = Ps[128 + j];
            }
            // consume iter k (A, W0)
            float fr = A0.z, fc = A0.w;
            float la = bf_lo(W0.ra);
            float va = la + fr * (bf_hi(W0.ra) - la);
            float w0 = bf2f(W0.pa) * va * fc;
            m0 += w0;
            float lb = bf_lo(W0.rb);
            float vb = lb + fr * (bf_hi(W0.rb) - lb);
            float w1 = bf2f(W0.pb) * vb * fc;
            m1a[0] += w1 * A1.x;
            m1a[1] += w1 * A1.y;
            m1a[2] += w1 * A1.z;
            float lc = bf_lo(W0.rc);
            float vc = lc + fr * (bf_hi(W0.rc) - lc);
            float w2 = bf2f(W0.pc) * vc * fc;
            m2a[0] += w2 * A1.w;
            m2a[1] += w2 * A2.x;
            m2a[2] += w2 * A2.y;
            m2a[3] += w2 * A2.z;
            m2a[4] += w2 * A2.w;

            A0 = B0; A1 = B1; A2 = B2;
            B0 = C0; B1 = C1; B2 = C2;
            C0 = D0; C1 = D1; C2 = D2;
            W0 = W1; W1 = W2;
        }
    }

    __shared__ float mbuf[2][576];
    mbuf[w][j] = m0;
    #pragma unroll
    for (int d = 0; d < 3; ++d) mbuf[w][64 + d * 64 + j] = m1a[d];
    #pragma unroll
    for (int d = 0; d < 5; ++d) mbuf[w][256 + d * 64 + j] = m2a[d];
    __syncthreads();
    for (int c = t; c < 576; c += 128)
        msum[(size_t)n * 576 + c] = mbuf[0][c] + mbuf[1][c];
}

// ---------- output transform: x += res * (msum @ blockdiag(Wo)) ----------
__global__ __launch_bounds__(512, 2) void k_out(const float* __restrict__ msum,
                                                const float* __restrict__ Wo0,
                                                const float* __restrict__ Wo1,
                                                const float* __restrict__ Wo2,
                                                const float* __restrict__ res_scale, int b,
                                                float* __restrict__ x) {
    int o = threadIdx.x;           // 0..511 (only o<480 compute)
    int n0 = blockIdx.x * NPB;
    __shared__ float ms[NPB][576];

    const float4* srcv = (const float4*)(msum + (size_t)n0 * 576);
    float4* dstv = (float4*)&ms[0][0];
    for (int i = threadIdx.x; i < NPB * 576 / 4; i += 512) dstv[i] = srcv[i];
    __syncthreads();

    if (o < DIMN) {
        const float* W;
        int stride, mbase;
        if (o < M0) {
            W = Wo0 + o; stride = M0; mbase = 0;
        } else if (o < M0 + 3 * M1) {
            int q = o - M0, k = q / 3, d = q - 3 * k;
            W = Wo1 + k; stride = M1; mbase = 64 + d * 64;
        } else {
            int q = o - (M0 + 3 * M1), k = q / 5, d = q - 5 * k;
            W = Wo2 + k; stride = M2; mbase = 256 + d * 64;
        }
        float acc[NPB];
        #pragma unroll
        for (int u = 0; u < NPB; ++u) acc[u] = 0.0f;
        for (int c = 0; c < 64; ++c) {
            float wv = W[c * stride];
            float* msc = &ms[0][mbase + c];
            #pragma unroll
            for (int u = 0; u < NPB; ++u) acc[u] += msc[u * 576] * wv;
        }
        float rs = res_scale[b];
        #pragma unroll
        for (int u = 0; u < NPB; ++u)
            x[(size_t)(n0 + u) * DIMN + o] += rs * acc[u];
    }
}

// ---------- final irrep norm + mask ----------
__global__ __launch_bounds__(64) void k_norm(const float* __restrict__ x,
                                             const float* __restrict__ mask,
                                             float* __restrict__ out) {
    int n = blockIdx.x;
    int j = threadIdx.x;
    const float* xn = x + (size_t)n * DIMN;
    float s0 = 0, s1 = 0, s2 = 0;
    for (int c = j; c < 128; c += 64) { float v = xn[c]; s0 += v * v; }
    for (int c = j; c < 192; c += 64) { float v = xn[128 + c]; s1 += v * v; }
    for (int c = j; c < 160; c += 64) { float v = xn[320 + c]; s2 += v * v; }
    for (int d = 32; d > 0; d >>= 1) {
        s0 += __shfl_down(s0, d);
        s1 += __shfl_down(s1, d);
        s2 += __shfl_down(s2, d);
    }
    __shared__ float inv0, inv1, inv2;
    if (j == 0) {
        inv0 = rsqrtf(s0 / (float)M0 + 1e-6f);
        inv1 = rsqrtf(s1 / (float)M1 + 1e-6f);
        inv2 = rsqrtf(s2 / (float)M2 + 1e-6f);
    }
    __syncthreads();
    float fm = mask[n];
    float* on = out + (size_t)n * DIMN;
    for (int c = j; c < 128; c += 64) on[c] = xn[c] * inv0 * fm;
    for (int c = j; c < 192; c += 64) on[128 + c] = xn[128 + c] * inv1 * fm;
    for (int c = j; c < 160; c += 64) on[320 + c] = xn[320 + c] * inv2 * fm;
}

extern "C" void kernel_launch(void* const* d_in, const int* in_sizes, int n_in,
                              void* d_out, int out_size, void* d_ws, size_t ws_size,
                              hipStream_t stream) {
    const int*   z    = (const int*)d_in[0];
    const float* mask = (const float*)d_in[1];
    const int*   esrc = (const int*)d_in[2];
    const int*   edst = (const int*)d_in[3];
    const float* ew   = (const float*)d_in[4];
    const float* ev   = (const float*)d_in[5];
    const float* zemb = (const float*)d_in[6];
    const float* Win  = (const float*)d_in[7];
    const float* Wp   = (const float*)d_in[8];
    const float* rW1  = (const float*)d_in[9];
    const float* rb1  = (const float*)d_in[10];
    const float* rW2  = (const float*)d_in[11];
    const float* rb2  = (const float*)d_in[12];
    const float* Wo0  = (const float*)d_in[13];
    const float* Wo1  = (const float*)d_in[14];
    const float* Wo2  = (const float*)d_in[15];
    const float* res  = (const float*)d_in[16];

    const int BN = in_sizes[0];      // 4096
    const int E  = in_sizes[2];      // 131072

    // ---- workspace carve ----
    char* w = (char*)d_ws;
    float* x    = (float*)w;  w += (size_t)BN * DIMN * 4;            // 7.86 MB
    u16*   P    = (u16*)w;    w += (size_t)BN * 192 * 2;             // 1.57 MB
    float* rS   = (float*)w;  w += (size_t)NBLK * NT * 192 * 4;      // 4.72 MB
    u32*   rP   = (u32*)w;    w += (size_t)NBLK * NT * 192 * 4;      // 4.72 MB
    ERec*  rec  = (ERec*)w;   w += (size_t)E * sizeof(ERec);         // 6.29 MB
    float* msum = (float*)w;  w += (size_t)BN * 576 * 4;             // 9.44 MB
    int* counts = (int*)w;   w += (size_t)BN * 4;
    int* offs   = (int*)w;   w += (size_t)(BN + 4) * 4;
    int* cursor = (int*)w;   w += (size_t)BN * 4;

    k_zero<<<(BN + 255) / 256, 256, 0, stream>>>(counts, BN);
    k_count<<<(E + 255) / 256, 256, 0, stream>>>(edst, counts, E);
    k_scan<<<1, 1024, 0, stream>>>(counts, offs, cursor, BN);
    k_build<<<(E + 255) / 256, 256, 0, stream>>>(ew, ev, esrc, edst, cursor, rec, E);
    k_initx<<<BN, 128, 0, stream>>>(z, mask, zemb, Win, x);
    k_rtab<<<NBLK * (NT / TCHUNK), 256, 0, stream>>>(rW1, rb1, rW2, rb2, rS);
    {
        int total = NBLK * NT * 192;
        k_pack<<<(total + 255) / 256, 256, 0, stream>>>(rS, rP, total);
    }

    for (int b = 0; b < NBLK; ++b) {
        k_proj<<<BN / NNP, 192, 0, stream>>>(x, Wp + (size_t)b * M0 * 192, P);
        k_gather<<<BN, 128, 0, stream>>>(P, rP + (size_t)b * NT * 192, rec, offs, msum);
        k_out<<<BN / NPB, 512, 0, stream>>>(msum,
                                            Wo0 + (size_t)b * MSGC * M0,
                                            Wo1 + (size_t)b * MSGC * M1,
                                            Wo2 + (size_t)b * MSGC * M2,
                                            res, b, x);
    }

    k_norm<<<BN, 64, 0, stream>>>(x, mask, (float*)d_out);
}